// Round 9
// baseline (292.225 us; speedup 1.0000x reference)
//
#include <hip/hip_runtime.h>
#include <hip/hip_bf16.h>
#include <stdint.h>

// Problem constants (b=16, l=4096, d=256, c=256, qk_dim=256, heads=8)
// Inputs: float32. Outputs: FLOAT32:
//   out[0..65536)       k  [8,256,32]
//   out[65536..131072)  v  [8,256,32]
//   out[131072..196608) x_global [256,256]
#define DD 256
#define CC 256

typedef __attribute__((ext_vector_type(8))) short bf16x8;
typedef __attribute__((ext_vector_type(4))) float f32x4;

// round-to-nearest-even f32 -> bf16; also returns the rounded value as f32
__device__ __forceinline__ unsigned short bf16_rn(float v, float& hval) {
    unsigned u = __builtin_bit_cast(unsigned, v);
    unsigned r = u + 0x7FFFu + ((u >> 16) & 1u);
    hval = __builtin_bit_cast(float, r & 0xFFFF0000u);
    return (unsigned short)(r >> 16);
}

// ---------------------------------------------------------------------------
// K1: normalize cluster means (f32); emit packed split-bf16 slices:
// mpk[kc(8)][ hi: [q(4)][c(256)][8] | lo: same ] (32KB per kc slice,
// contiguous for global_load_lds). Zero sums + bins.
__global__ __launch_bounds__(256) void k_prep(const float* __restrict__ xm,
                                              float* __restrict__ means_n,
                                              unsigned short* __restrict__ mpk,
                                              float* __restrict__ sums,
                                              int* __restrict__ bins) {
    __shared__ float red[256];
    int c = blockIdx.x, t = threadIdx.x;
    float v = xm[c * DD + t];
    red[t] = v * v;
    __syncthreads();
    for (int off = 128; off > 0; off >>= 1) {
        if (t < off) red[t] += red[t + off];
        __syncthreads();
    }
    float inv = 1.0f / fmaxf(sqrtf(red[0]), 1e-12f);
    float vn = v * inv;
    means_n[c * DD + t] = vn;
    float hf; unsigned short hb = bf16_rn(vn, hf);
    float lo = vn - hf;                 // exact
    float d2; unsigned short lb = bf16_rn(lo, d2);
    int kc = t >> 5, q = (t >> 3) & 3, j = t & 7;
    mpk[kc * 16384 + q * 2048 + c * 8 + j]        = hb;
    mpk[kc * 16384 + 8192 + q * 2048 + c * 8 + j] = lb;
    sums[c * DD + t] = 0.0f;
    if (c == 0) bins[t] = 0;
}

// ---------------------------------------------------------------------------
// K2 v5: MFMA similarity + argmax + inv-norm + bins.
// R8 lesson: MfmaUtil pinned ~10% across structures with only ~8 waves/CU
// resident -- latency can't be hidden without waves (m114). v5: 512-thread
// blocks (8 waves) sharing ONE 2x32KB double buffer: LDS/CU unchanged
// (2 blocks x 64KB = 128KB), waves/CU doubles to 16 (4/SIMD). Stage work
// splits 8 ways (4 global_load_lds per wave). One barrier per kc:
// barrier(stage kc landed) -> issue stage(kc+1) other buffer -> compute(kc).
// ~120 unified regs (56V + 64A) -> 4 waves/SIMD fits (480<=512).
// 3-MFMA split-bf16 (hh+lh+hl): buckets bit-identical to f32 ref (R4-R8).
// C/D layout: cluster=ct*16+(lane&15), point=p0+q*4+reg.
__global__ __launch_bounds__(512, 4) void k_assign(
        const float* __restrict__ x,
        const unsigned short* __restrict__ mpk,
        int* __restrict__ buckets,
        float* __restrict__ inv_norm,
        int* __restrict__ bins) {
    __shared__ __align__(16) unsigned short mlds[2][16384];   // 2 x 32KB
    int t = threadIdx.x;
    int w = t >> 6, lane = t & 63;             // w in 0..7
    int m = lane & 15, q = lane >> 4;          // q in 0..3
    int p0 = blockIdx.x * 128 + w * 16;
    const float* xq = x + (size_t)(p0 + m) * DD + q * 8;

    f32x4 acc[16];
#pragma unroll
    for (int ct = 0; ct < 16; ct++) acc[ct] = (f32x4){0.f, 0.f, 0.f, 0.f};
    float ss = 0.f;

    // stage kc slice into buffer BUF: 32KB/block, 4KB/wave = 4 x (64 x 16B)
#define STAGE(KC, BUF) do {                                                     \
        const unsigned short* gsrc = mpk + (KC) * 16384 + w * 2048 + lane * 8;  \
        unsigned short* lb = &mlds[BUF][w * 2048];                              \
        _Pragma("unroll")                                                       \
        for (int i = 0; i < 4; i++)                                             \
            __builtin_amdgcn_global_load_lds(                                   \
                (const __attribute__((address_space(1))) void*)(gsrc + i * 512),\
                (__attribute__((address_space(3))) void*)(lb + i * 512),        \
                16, 0, 0);                                                      \
    } while (0)

    STAGE(0, 0);
    float4 nxa = *(const float4*)(xq);
    float4 nxb = *(const float4*)(xq + 4);

    for (int kc = 0; kc < 8; kc++) {
        __syncthreads();   // stage(kc) landed; all waves done with other buf

        if (kc < 7) STAGE(kc + 1, (kc + 1) & 1);   // prefetch under compute

        float4 xa = nxa, xb = nxb;
        ss += xa.x * xa.x + xa.y * xa.y + xa.z * xa.z + xa.w * xa.w +
              xb.x * xb.x + xb.y * xb.y + xb.z * xb.z + xb.w * xb.w;
        float xv[8] = {xa.x, xa.y, xa.z, xa.w, xb.x, xb.y, xb.z, xb.w};
        bf16x8 ah, al;
#pragma unroll
        for (int j = 0; j < 8; j++) {
            float hf; unsigned short hb = bf16_rn(xv[j], hf);
            float lo = xv[j] - hf; float d2;
            al[j] = (short)bf16_rn(lo, d2); ah[j] = (short)hb;
        }
        if (kc < 7) {   // x prefetch: lands long before next barrier
            nxa = *(const float4*)(xq + (kc + 1) * 32);
            nxb = *(const float4*)(xq + (kc + 1) * 32 + 4);
        }

        const unsigned short* fb = &mlds[kc & 1][q * 2048 + m * 8];
#pragma unroll
        for (int ct = 0; ct < 16; ct++) {
            bf16x8 bh = *(const bf16x8*)(fb + ct * 128);
            bf16x8 bl = *(const bf16x8*)(fb + 8192 + ct * 128);
            acc[ct] = __builtin_amdgcn_mfma_f32_16x16x32_bf16(ah, bh, acc[ct], 0, 0, 0);
            acc[ct] = __builtin_amdgcn_mfma_f32_16x16x32_bf16(al, bh, acc[ct], 0, 0, 0);
            acc[ct] = __builtin_amdgcn_mfma_f32_16x16x32_bf16(ah, bl, acc[ct], 0, 0, 0);
        }
    }
#undef STAGE

    // row inv-norm: sum over the 4 q-lane groups (lane bits 4,5)
    ss += __shfl_xor(ss, 16, 64);
    ss += __shfl_xor(ss, 32, 64);
    if (q == 0) inv_norm[p0 + m] = 1.0f / fmaxf(sqrtf(ss), 1e-12f);

    // argmax: per-lane over ascending ct (strict > keeps lowest cluster)
    float bv[4]; int bi[4];
#pragma unroll
    for (int r = 0; r < 4; r++) {
        bv[r] = acc[0][r]; bi[r] = m;
#pragma unroll
        for (int ct = 1; ct < 16; ct++) {
            float v2 = acc[ct][r];
            if (v2 > bv[r]) { bv[r] = v2; bi[r] = ct * 16 + m; }
        }
    }
    // reduce across the 16 m-lanes; tie -> lowest cluster index
#pragma unroll
    for (int mask = 1; mask < 16; mask <<= 1) {
#pragma unroll
        for (int r = 0; r < 4; r++) {
            float ov = __shfl_xor(bv[r], mask, 64);
            int   oi = __shfl_xor(bi[r], mask, 64);
            if (ov > bv[r] || (ov == bv[r] && oi < bi[r])) { bv[r] = ov; bi[r] = oi; }
        }
    }
    if (m == 0) {
#pragma unroll
        for (int r = 0; r < 4; r++) {
            buckets[p0 + q * 4 + r] = bi[r];
            atomicAdd(&bins[bi[r]], 1);
        }
    }
}

// ---------------------------------------------------------------------------
// K3 v2: scatter-add of normalized x into sums.
// R8 lesson: 96us at 527 GB/s, VALUBusy 5%, occ 17% -- latency-bound with
// per-iteration dependent loads and only 2 blocks/CU. v2: (a) grid (128,8)
// = 1024 blocks -> 4 blocks/CU (slab 32KB + 4KB preload = 36KB); (b) buckets
// + inv_norm preloaded coalesced into LDS (inner loop = pure x streaming);
// (c) unroll-8 batched loads -> 8 outstanding 128B segments per wave.
__global__ __launch_bounds__(256) void k_scatter(const float* __restrict__ x,
                                                 const int* __restrict__ buckets,
                                                 const float* __restrict__ inv_norm,
                                                 float* __restrict__ sums) {
    __shared__ float acc[256 * 32];   // 32KB slab [cluster][coord]
    __shared__ int   lb[512];         // 2KB
    __shared__ float lw[512];         // 2KB
    int t = threadIdx.x;
    for (int i = t; i < 8192; i += 256) acc[i] = 0.0f;
    int n0 = blockIdx.x * 512;
    {   // coalesced preload of this chunk's buckets + inv_norm
        int2   b2 = ((const int2*)(buckets + n0))[t];
        float2 w2 = ((const float2*)(inv_norm + n0))[t];
        lb[2 * t]     = b2.x & 255;
        lb[2 * t + 1] = b2.y & 255;
        lw[2 * t]     = w2.x;
        lw[2 * t + 1] = w2.y;
    }
    __syncthreads();
    int co = t & 31, pg = t >> 5;               // 8 point-groups
    int c0 = blockIdx.y * 32;
    const float* xb = x + (size_t)n0 * DD + c0 + co;
    for (int i = 0; i < 64; i += 8) {
        float v[8]; int bb[8];
#pragma unroll
        for (int j = 0; j < 8; j++) {
            int p = (i + j) * 8 + pg;           // point within chunk
            v[j]  = xb[(size_t)p * DD] * lw[p]; // lw: LDS broadcast (uniform/half-wave)
            bb[j] = lb[p];
        }
#pragma unroll
        for (int j = 0; j < 8; j++) atomicAdd(&acc[bb[j] * 32 + co], v[j]);
    }
    __syncthreads();
    for (int k2 = 0; k2 < 32; k2++) {
        int flat = k2 * 256 + t;
        atomicAdd(&sums[(flat >> 5) * DD + c0 + (flat & 31)], acc[flat]);
    }
}

// ---------------------------------------------------------------------------
// K4+K5 fused: x_global = l2norm(sums) (or old mean if empty bin), then
// k = xg @ Wk^T, v = xg @ Wv^T in [h][c][dh] layout. All f32. 256 blocks.
__global__ __launch_bounds__(256) void k_xgkv(const float* __restrict__ sums,
                                              const int* __restrict__ bins,
                                              const float* __restrict__ means_n,
                                              const float* __restrict__ Wk,
                                              const float* __restrict__ Wv,
                                              float* __restrict__ out) {
    __shared__ float red[256];
    __shared__ __align__(16) float xr[256];
    int c = blockIdx.x, t = threadIdx.x;
    float s = sums[c * DD + t];
    red[t] = s * s;
    __syncthreads();
    for (int off = 128; off > 0; off >>= 1) {
        if (t < off) red[t] += red[t + off];
        __syncthreads();
    }
    float g;
    if (bins[c] > 0) g = s / fmaxf(sqrtf(red[0]), 1e-12f);
    else             g = means_n[c * DD + t];
    out[131072 + c * DD + t] = g;   // output 2: x_global
    xr[t] = g;
    __syncthreads();

    float ak = 0.f, av = 0.f;
    const float4* wkp = (const float4*)(Wk + (size_t)t * DD);
    const float4* wvp = (const float4*)(Wv + (size_t)t * DD);
#pragma unroll 8
    for (int j4 = 0; j4 < 64; j4++) {
        float4 wk = wkp[j4], wv = wvp[j4];
        float4 a = *(const float4*)(xr + j4 * 4);
        ak += a.x * wk.x + a.y * wk.y + a.z * wk.z + a.w * wk.w;
        av += a.x * wv.x + a.y * wv.y + a.z * wv.z + a.w * wv.w;
    }
    int h = t >> 5, dh = t & 31;
    out[h * 8192 + c * 32 + dh]         = ak;   // output 0: k
    out[65536 + h * 8192 + c * 32 + dh] = av;   // output 1: v
}

// ---------------------------------------------------------------------------
extern "C" void kernel_launch(void* const* d_in, const int* in_sizes, int n_in,
                              void* d_out, int out_size, void* d_ws, size_t ws_size,
                              hipStream_t stream) {
    (void)in_sizes; (void)n_in; (void)out_size; (void)ws_size;
    const float* x  = (const float*)d_in[0];  // [16,4096,256] f32
    const float* xm = (const float*)d_in[1];  // [256,256] f32
    const float* Wk = (const float*)d_in[2];  // [256,256] f32
    const float* Wv = (const float*)d_in[3];  // [256,256] f32

    float* ws       = (float*)d_ws;
    float* means_n  = ws;                     // 65536 f32
    float* inv_norm = ws + 65536;             // 65536 f32
    int*   buckets  = (int*)(ws + 131072);    // 65536 int
    float* sums     = ws + 196608;            // 65536 f32
    int*   bins     = (int*)(ws + 262144);    // 256 int
    unsigned short* mpk = (unsigned short*)(ws + 262400);  // 131072 bf16 (256KB)
    float* out      = (float*)d_out;

    k_prep   <<<256, 256, 0, stream>>>(xm, means_n, mpk, sums, bins);
    k_assign <<<512, 512, 0, stream>>>(x, mpk, buckets, inv_norm, bins);
    k_scatter<<<dim3(128, 8), 256, 0, stream>>>(x, buckets, inv_norm, sums);
    k_xgkv   <<<256, 256, 0, stream>>>(sums, bins, means_n, Wk, Wv, out);
}

// Round 10
// 265.804 us; speedup vs baseline: 1.0994x; 1.0994x over previous
//
#include <hip/hip_runtime.h>
#include <hip/hip_bf16.h>
#include <stdint.h>

// Problem constants (b=16, l=4096, d=256, c=256, qk_dim=256, heads=8)
// Inputs: float32. Outputs: FLOAT32:
//   out[0..65536)       k  [8,256,32]
//   out[65536..131072)  v  [8,256,32]
//   out[131072..196608) x_global [256,256]
#define DD 256
#define CC 256

typedef __attribute__((ext_vector_type(8))) short bf16x8;
typedef __attribute__((ext_vector_type(4))) float f32x4;

// round-to-nearest-even f32 -> bf16; also returns the rounded value as f32
__device__ __forceinline__ unsigned short bf16_rn(float v, float& hval) {
    unsigned u = __builtin_bit_cast(unsigned, v);
    unsigned r = u + 0x7FFFu + ((u >> 16) & 1u);
    hval = __builtin_bit_cast(float, r & 0xFFFF0000u);
    return (unsigned short)(r >> 16);
}

// ---------------------------------------------------------------------------
// K1: normalize cluster means (f32); emit split-bf16 packed per 64-cluster
// GROUP for the barrier-free assign kernel:
//   mpk2[g(4)][ hi: [kc(8)][q(4)][ct(4)][m(16)][8] | lo: same ]  (64KB/group)
// cluster c = g*64 + ct*16 + m ; dim d = kc*32 + q*8 + j.
// Also zero sums + bins + pk (packed argmax cells).
__global__ __launch_bounds__(256) void k_prep(const float* __restrict__ xm,
                                              float* __restrict__ means_n,
                                              unsigned short* __restrict__ mpk2,
                                              unsigned long long* __restrict__ pk,
                                              float* __restrict__ sums,
                                              int* __restrict__ bins) {
    __shared__ float red[256];
    int c = blockIdx.x, t = threadIdx.x;
    float v = xm[c * DD + t];
    red[t] = v * v;
    __syncthreads();
    for (int off = 128; off > 0; off >>= 1) {
        if (t < off) red[t] += red[t + off];
        __syncthreads();
    }
    float inv = 1.0f / fmaxf(sqrtf(red[0]), 1e-12f);
    float vn = v * inv;
    means_n[c * DD + t] = vn;
    float hf; unsigned short hb = bf16_rn(vn, hf);
    float lo = vn - hf;                 // exact
    float d2; unsigned short lb = bf16_rn(lo, d2);
    int g = c >> 6, ct = (c >> 4) & 3, m = c & 15;
    int kc = t >> 5, q = (t >> 3) & 3, j = t & 7;
    size_t base = (size_t)g * 32768 + ((kc * 4 + q) * 64 + ct * 16 + m) * 8 + j;
    mpk2[base]         = hb;            // hi half
    mpk2[base + 16384] = lb;            // lo half
    sums[c * DD + t] = 0.0f;
    pk[c * 256 + t] = 0ull;             // 0 == -NaN sentinel, below all reals
    if (c == 0) bins[t] = 0;
}

// ---------------------------------------------------------------------------
// K2 v6: BARRIER-FREE MFMA similarity (cluster-split) + packed-atomicMax argmax.
// R9 lesson: every double-buffer variant pinned at ~96us / MfmaUtil 10% --
// the kc-loop barrier convoy (8 waves x 8 barriers, x-prefetch drained in
// vmcnt(0), only 2 blocks/CU) was the invariant. v6 removes the barrier:
// block = 8 waves, stages 64 clusters x full K (hi+lo = exactly 64KB LDS)
// ONCE, then waves free-run. Wave owns 32 points (2 A-tiles): acc = 32 AGPR,
// ~100 unified regs -> 4 waves/SIMD, 2 blocks/CU = 16 waves. grid.y = 4
// cluster-groups; partial winners merged via u64 atomicMax of
// (orderable(val)<<32)|(255-cluster)  => max val, tie -> lowest cluster.
// 3-MFMA split-bf16 (hh+lh+hl): dists bit-identical to R5-R9.
// C/D layout: cluster_in_group=ct*16+(lane&15), point=tile_p0+q*4+reg.
__global__ __launch_bounds__(512, 4) void k_assign(
        const float* __restrict__ x,
        const unsigned short* __restrict__ mpk2,
        unsigned long long* __restrict__ pk,
        float* __restrict__ inv_norm) {
    __shared__ __align__(16) unsigned short mlds[32768];   // 64KB
    int t = threadIdx.x;
    int w = t >> 6, lane = t & 63;             // w in 0..7
    int m = lane & 15, q = lane >> 4;          // q in 0..3
    int g = blockIdx.y;                        // cluster group (64 clusters)
    int p0 = blockIdx.x * 256 + w * 32;
    const float* xq0 = x + (size_t)(p0 + m) * DD + q * 8;
    const float* xq1 = xq0 + 16 * DD;

    // one-time stage: 64KB, 8 instr/thread, wave-uniform LDS base (16B/lane)
    {
        const unsigned short* gsrc = mpk2 + (size_t)g * 32768 + w * 4096 + lane * 8;
        unsigned short* lb = mlds + w * 4096;
#pragma unroll
        for (int i = 0; i < 8; i++)
            __builtin_amdgcn_global_load_lds(
                (const __attribute__((address_space(1))) void*)(gsrc + i * 512),
                (__attribute__((address_space(3))) void*)(lb + i * 512),
                16, 0, 0);
    }
    __syncthreads();   // the ONLY barrier

    f32x4 acc0[4], acc1[4];
#pragma unroll
    for (int ct = 0; ct < 4; ct++) {
        acc0[ct] = (f32x4){0.f, 0.f, 0.f, 0.f};
        acc1[ct] = (f32x4){0.f, 0.f, 0.f, 0.f};
    }
    float ss0 = 0.f, ss1 = 0.f;

#pragma unroll 2
    for (int kc = 0; kc < 8; kc++) {
        float4 xa0 = *(const float4*)(xq0 + kc * 32);
        float4 xb0 = *(const float4*)(xq0 + kc * 32 + 4);
        float4 xa1 = *(const float4*)(xq1 + kc * 32);
        float4 xb1 = *(const float4*)(xq1 + kc * 32 + 4);
        ss0 += xa0.x * xa0.x + xa0.y * xa0.y + xa0.z * xa0.z + xa0.w * xa0.w +
               xb0.x * xb0.x + xb0.y * xb0.y + xb0.z * xb0.z + xb0.w * xb0.w;
        ss1 += xa1.x * xa1.x + xa1.y * xa1.y + xa1.z * xa1.z + xa1.w * xa1.w +
               xb1.x * xb1.x + xb1.y * xb1.y + xb1.z * xb1.z + xb1.w * xb1.w;
        float xv0[8] = {xa0.x, xa0.y, xa0.z, xa0.w, xb0.x, xb0.y, xb0.z, xb0.w};
        float xv1[8] = {xa1.x, xa1.y, xa1.z, xa1.w, xb1.x, xb1.y, xb1.z, xb1.w};
        bf16x8 ah0, al0, ah1, al1;
#pragma unroll
        for (int j = 0; j < 8; j++) {
            float hf; unsigned short hb = bf16_rn(xv0[j], hf);
            float lo = xv0[j] - hf; float d2;
            al0[j] = (short)bf16_rn(lo, d2); ah0[j] = (short)hb;
            hb = bf16_rn(xv1[j], hf);
            lo = xv1[j] - hf;
            al1[j] = (short)bf16_rn(lo, d2); ah1[j] = (short)hb;
        }

        const unsigned short* fb = mlds + (kc * 4 + q) * 512 + m * 8;
#pragma unroll
        for (int ct = 0; ct < 4; ct++) {
            bf16x8 bh = *(const bf16x8*)(fb + ct * 128);
            bf16x8 bl = *(const bf16x8*)(fb + 16384 + ct * 128);
            acc0[ct] = __builtin_amdgcn_mfma_f32_16x16x32_bf16(ah0, bh, acc0[ct], 0, 0, 0);
            acc0[ct] = __builtin_amdgcn_mfma_f32_16x16x32_bf16(al0, bh, acc0[ct], 0, 0, 0);
            acc0[ct] = __builtin_amdgcn_mfma_f32_16x16x32_bf16(ah0, bl, acc0[ct], 0, 0, 0);
            acc1[ct] = __builtin_amdgcn_mfma_f32_16x16x32_bf16(ah1, bh, acc1[ct], 0, 0, 0);
            acc1[ct] = __builtin_amdgcn_mfma_f32_16x16x32_bf16(al1, bh, acc1[ct], 0, 0, 0);
            acc1[ct] = __builtin_amdgcn_mfma_f32_16x16x32_bf16(ah1, bl, acc1[ct], 0, 0, 0);
        }
    }

    // row inv-norms (only group 0 computes/writes them)
    if (g == 0) {
        ss0 += __shfl_xor(ss0, 16, 64); ss0 += __shfl_xor(ss0, 32, 64);
        ss1 += __shfl_xor(ss1, 16, 64); ss1 += __shfl_xor(ss1, 32, 64);
        if (q == 0) {
            inv_norm[p0 + m]      = 1.0f / fmaxf(sqrtf(ss0), 1e-12f);
            inv_norm[p0 + 16 + m] = 1.0f / fmaxf(sqrtf(ss1), 1e-12f);
        }
    }

    // per-lane argmax over ascending ct (strict > keeps lowest cluster)
    float bv0[4], bv1[4]; int bi0[4], bi1[4];
#pragma unroll
    for (int r = 0; r < 4; r++) {
        bv0[r] = acc0[0][r]; bi0[r] = m;
        bv1[r] = acc1[0][r]; bi1[r] = m;
#pragma unroll
        for (int ct = 1; ct < 4; ct++) {
            float v2 = acc0[ct][r];
            if (v2 > bv0[r]) { bv0[r] = v2; bi0[r] = ct * 16 + m; }
            float v3 = acc1[ct][r];
            if (v3 > bv1[r]) { bv1[r] = v3; bi1[r] = ct * 16 + m; }
        }
    }
    // reduce across the 16 m-lanes; tie -> lowest cluster index
#pragma unroll
    for (int mask = 1; mask < 16; mask <<= 1) {
#pragma unroll
        for (int r = 0; r < 4; r++) {
            float ov = __shfl_xor(bv0[r], mask, 64);
            int   oi = __shfl_xor(bi0[r], mask, 64);
            if (ov > bv0[r] || (ov == bv0[r] && oi < bi0[r])) { bv0[r] = ov; bi0[r] = oi; }
            ov = __shfl_xor(bv1[r], mask, 64);
            oi = __shfl_xor(bi1[r], mask, 64);
            if (ov > bv1[r] || (ov == bv1[r] && oi < bi1[r])) { bv1[r] = ov; bi1[r] = oi; }
        }
    }
    if (m == 0) {
#pragma unroll
        for (int r = 0; r < 4; r++) {
            // pack: orderable float in high 32, (255 - cluster) low => max val,
            // ties -> lowest global cluster index (first-occurrence semantics)
            unsigned ub0 = __builtin_bit_cast(unsigned, bv0[r]);
            ub0 = (ub0 & 0x80000000u) ? ~ub0 : (ub0 | 0x80000000u);
            unsigned long long pv0 = ((unsigned long long)ub0 << 32)
                                   | (unsigned)(255 - (g * 64 + bi0[r]));
            atomicMax(&pk[p0 + q * 4 + r], pv0);
            unsigned ub1 = __builtin_bit_cast(unsigned, bv1[r]);
            ub1 = (ub1 & 0x80000000u) ? ~ub1 : (ub1 | 0x80000000u);
            unsigned long long pv1 = ((unsigned long long)ub1 << 32)
                                   | (unsigned)(255 - (g * 64 + bi1[r]));
            atomicMax(&pk[p0 + 16 + q * 4 + r], pv1);
        }
    }
}

// ---------------------------------------------------------------------------
// K3 v3: scatter-add of normalized x into sums. Decodes buckets from pk.
// grid (256 point-chunks, 8 coord-chunks) = 2048 blocks (~4/CU, 35KB LDS).
// buckets+inv_norm preloaded to LDS; unroll-16 load batches for MLP.
// blockIdx.y==0 blocks also accumulate bins (histogram) for k_xgkv.
__global__ __launch_bounds__(256) void k_scatter(const float* __restrict__ x,
                                                 const unsigned long long* __restrict__ pk,
                                                 const float* __restrict__ inv_norm,
                                                 float* __restrict__ sums,
                                                 int* __restrict__ bins) {
    __shared__ float acc[256 * 32];   // 32KB slab [cluster][coord]
    __shared__ int   lb[256];
    __shared__ float lw[256];
    __shared__ int   hist[256];
    int t = threadIdx.x;
    for (int i = t; i < 8192; i += 256) acc[i] = 0.0f;
    hist[t] = 0;
    int n0 = blockIdx.x * 256;
    {   // decode this chunk's buckets + load inv_norm (coalesced)
        unsigned long long v = pk[n0 + t];
        lb[t] = 255 - (int)(v & 0xFFu);   // low 32 bits = 255 - cluster
        lw[t] = inv_norm[n0 + t];
    }
    __syncthreads();
    if (blockIdx.y == 0) atomicAdd(&hist[lb[t]], 1);   // LDS histogram
    int co = t & 31, pg = t >> 5;               // 8 point-groups
    int c0 = blockIdx.y * 32;
    const float* xb = x + (size_t)n0 * DD + c0 + co;
    for (int i = 0; i < 32; i += 16) {
        float v[16]; int bb[16];
#pragma unroll
        for (int j = 0; j < 16; j++) {
            int p = (i + j) * 8 + pg;           // point within chunk
            v[j]  = xb[(size_t)p * DD] * lw[p];
            bb[j] = lb[p];
        }
#pragma unroll
        for (int j = 0; j < 16; j++) atomicAdd(&acc[bb[j] * 32 + co], v[j]);
    }
    __syncthreads();
    for (int k2 = 0; k2 < 32; k2++) {
        int flat = k2 * 256 + t;
        atomicAdd(&sums[(flat >> 5) * DD + c0 + (flat & 31)], acc[flat]);
    }
    if (blockIdx.y == 0 && hist[t] > 0) atomicAdd(&bins[t], hist[t]);
}

// ---------------------------------------------------------------------------
// K4+K5 fused: x_global = l2norm(sums) (or old mean if empty bin), then
// k = xg @ Wk^T, v = xg @ Wv^T in [h][c][dh] layout. All f32. 256 blocks.
__global__ __launch_bounds__(256) void k_xgkv(const float* __restrict__ sums,
                                              const int* __restrict__ bins,
                                              const float* __restrict__ means_n,
                                              const float* __restrict__ Wk,
                                              const float* __restrict__ Wv,
                                              float* __restrict__ out) {
    __shared__ float red[256];
    __shared__ __align__(16) float xr[256];
    int c = blockIdx.x, t = threadIdx.x;
    float s = sums[c * DD + t];
    red[t] = s * s;
    __syncthreads();
    for (int off = 128; off > 0; off >>= 1) {
        if (t < off) red[t] += red[t + off];
        __syncthreads();
    }
    float g;
    if (bins[c] > 0) g = s / fmaxf(sqrtf(red[0]), 1e-12f);
    else             g = means_n[c * DD + t];
    out[131072 + c * DD + t] = g;   // output 2: x_global
    xr[t] = g;
    __syncthreads();

    float ak = 0.f, av = 0.f;
    const float4* wkp = (const float4*)(Wk + (size_t)t * DD);
    const float4* wvp = (const float4*)(Wv + (size_t)t * DD);
#pragma unroll 8
    for (int j4 = 0; j4 < 64; j4++) {
        float4 wk = wkp[j4], wv = wvp[j4];
        float4 a = *(const float4*)(xr + j4 * 4);
        ak += a.x * wk.x + a.y * wk.y + a.z * wk.z + a.w * wk.w;
        av += a.x * wv.x + a.y * wv.y + a.z * wv.z + a.w * wv.w;
    }
    int h = t >> 5, dh = t & 31;
    out[h * 8192 + c * 32 + dh]         = ak;   // output 0: k
    out[65536 + h * 8192 + c * 32 + dh] = av;   // output 1: v
}

// ---------------------------------------------------------------------------
extern "C" void kernel_launch(void* const* d_in, const int* in_sizes, int n_in,
                              void* d_out, int out_size, void* d_ws, size_t ws_size,
                              hipStream_t stream) {
    (void)in_sizes; (void)n_in; (void)out_size; (void)ws_size;
    const float* x  = (const float*)d_in[0];  // [16,4096,256] f32
    const float* xm = (const float*)d_in[1];  // [256,256] f32
    const float* Wk = (const float*)d_in[2];  // [256,256] f32
    const float* Wv = (const float*)d_in[3];  // [256,256] f32

    float* ws       = (float*)d_ws;
    float* means_n  = ws;                                      // 65536 f32
    float* inv_norm = ws + 65536;                              // 65536 f32
    unsigned long long* pk = (unsigned long long*)(ws + 131072); // 65536 u64
    float* sums     = ws + 262144;                             // 65536 f32
    int*   bins     = (int*)(ws + 327680);                     // 256 int
    unsigned short* mpk2 = (unsigned short*)(ws + 327936);     // 131072 bf16
    float* out      = (float*)d_out;

    k_prep   <<<256, 256, 0, stream>>>(xm, means_n, mpk2, pk, sums, bins);
    k_assign <<<dim3(256, 4), 512, 0, stream>>>(x, mpk2, pk, inv_norm);
    k_scatter<<<dim3(256, 8), 256, 0, stream>>>(x, pk, inv_norm, sums, bins);
    k_xgkv   <<<256, 256, 0, stream>>>(sums, bins, means_n, Wk, Wv, out);
}